// Round 5
// baseline (316.888 us; speedup 1.0000x reference)
//
#include <hip/hip_runtime.h>

// Skeleton forward kinematics: angles [B,16,6] f32, xyz [1,16,3] f32 -> out [B,16,3] f32.
// R8: R3 EXACTLY + __launch_bounds__(256,4). Evidence chain:
//   R3 (64us/disp): VGPR=132, OccupancyPercent ~10%. 132 > 128 cliff -> 2 waves/SIMD
//       (8/CU). 17% VALU, 19% HBM: latency-bound, fill-concurrency-starved.
//   R4/R6: store coalescing (reg-batch / LDS+coop epilogue) both NULL -> VMEM request
//       rate is not the bottleneck.
//   R5: split-prefetch + (256,4) TOGETHER -> VGPR 64 + catastrophic spill (confounded:
//       the split structure needed ~150 live under a 128 cap). BUT it proved 2.7 TB/s
//       sustained at 35% occupancy -> throughput scales with resident waves.
//   R7: 15+9 split, no forcing -> VGPR 144 (worse). Structural splits perturb allocation UP.
// This round: ONE variable. R3's proven structure needs ~132 regs; cap at 128 forces a
// ~4-8 value spill (tens of B/thread, tolerable) and doubles occupancy to 4 waves/SIMD.
// Tripwire: if FETCH/WRITE balloon -> cascade spill -> launch-bounds unusable, go LDS route.

namespace {

constexpr int NJ = 16;

__device__ __forceinline__ void rot6d(const float* __restrict__ a, float R[9]) {
    float inv1 = rsqrtf(a[0]*a[0] + a[1]*a[1] + a[2]*a[2]);
    float b10 = a[0]*inv1, b11 = a[1]*inv1, b12 = a[2]*inv1;
    float d = b10*a[3] + b11*a[4] + b12*a[5];
    float c0 = a[3] - d*b10, c1 = a[4] - d*b11, c2 = a[5] - d*b12;
    float inv2 = rsqrtf(c0*c0 + c1*c1 + c2*c2);
    float b20 = c0*inv2, b21 = c1*inv2, b22 = c2*inv2;
    R[0] = b10; R[1] = b11; R[2] = b12;
    R[3] = b20; R[4] = b21; R[5] = b22;
    R[6] = b11*b22 - b12*b21;
    R[7] = b12*b20 - b10*b22;
    R[8] = b10*b21 - b11*b20;
}

__global__ __launch_bounds__(256, 4) void skel_kernel(
    const float* __restrict__ angles,
    const float* __restrict__ xyz,
    float* __restrict__ out,
    int batch)
{
    const int b = blockIdx.x * 256 + threadIdx.x;
    if (b >= batch) return;

    // ---- prefetch: 24 independent float4 loads (full 384 B of this element) ----
    const float4* a4 = (const float4*)(angles + (size_t)b * (NJ * 6));
    float4 v[24];
#pragma unroll
    for (int k = 0; k < 24; ++k) v[k] = a4[k];

    // Hard scheduling fence: nothing may move across. Loads above CANNOT sink
    // into the dependent chain below.
    __builtin_amdgcn_sched_barrier(0);

    float af[NJ * 6];
#pragma unroll
    for (int k = 0; k < 24; ++k) {
        af[4*k + 0] = v[k].x; af[4*k + 1] = v[k].y;
        af[4*k + 2] = v[k].z; af[4*k + 3] = v[k].w;
    }

    float* ob = out + (size_t)b * (NJ * 3);

    float R[9], Rw[9], pw[3], Rw3[9], pw3[3];

    // ---- joint 0 ----
    rot6d(&af[0], Rw);
    {
        float x = xyz[0], y = xyz[1], z = xyz[2];
        pw[0] = Rw[0]*x + Rw[1]*y + Rw[2]*z;
        pw[1] = Rw[3]*x + Rw[4]*y + Rw[5]*z;
        pw[2] = Rw[6]*x + Rw[7]*y + Rw[8]*z;
    }
    ob[0] = pw[0]; ob[1] = pw[1]; ob[2] = pw[2];

    // tree edges (parent -> child = e+1); chains 0-1-2-3, 3-4-5, 3-6..10, 3-11..15
    constexpr int PAR[15] = {0, 1, 2, 3, 4, 3, 6, 7, 8, 9, 3, 11, 12, 13, 14};

#pragma unroll
    for (int e = 0; e < 15; ++e) {
        const int c = e + 1;
        const int p = PAR[e];

        if (p == 3) {  // branch restart: restore saved state at joint 3
#pragma unroll
            for (int k = 0; k < 9; ++k) Rw[k] = Rw3[k];
            pw[0] = pw3[0]; pw[1] = pw3[1]; pw[2] = pw3[2];
        }

        rot6d(&af[c * 6], R);

        // t = ref[c] - ref[p] (wave-uniform scalar loads)
        float tx = xyz[c * 3 + 0] - xyz[p * 3 + 0];
        float ty = xyz[c * 3 + 1] - xyz[p * 3 + 1];
        float tz = xyz[c * 3 + 2] - xyz[p * 3 + 2];

        // local_t = R @ t
        float lt0 = R[0]*tx + R[1]*ty + R[2]*tz;
        float lt1 = R[3]*tx + R[4]*ty + R[5]*tz;
        float lt2 = R[6]*tx + R[7]*ty + R[8]*tz;

        // pw[c] = Rw[p] @ local_t + pw[p]
        float np0 = Rw[0]*lt0 + Rw[1]*lt1 + Rw[2]*lt2 + pw[0];
        float np1 = Rw[3]*lt0 + Rw[4]*lt1 + Rw[5]*lt2 + pw[1];
        float np2 = Rw[6]*lt0 + Rw[7]*lt1 + Rw[8]*lt2 + pw[2];

        // Rw[c] = Rw[p] @ R[c]
        float T[9];
#pragma unroll
        for (int i = 0; i < 3; ++i)
#pragma unroll
            for (int j = 0; j < 3; ++j)
                T[i*3 + j] = Rw[i*3 + 0]*R[0*3 + j]
                           + Rw[i*3 + 1]*R[1*3 + j]
                           + Rw[i*3 + 2]*R[2*3 + j];
#pragma unroll
        for (int k = 0; k < 9; ++k) Rw[k] = T[k];
        pw[0] = np0; pw[1] = np1; pw[2] = np2;

        // store immediately (fire-and-forget)
        ob[c*3 + 0] = np0; ob[c*3 + 1] = np1; ob[c*3 + 2] = np2;

        if (c == 3) {  // save branch point (children 4, 6, 11)
#pragma unroll
            for (int k = 0; k < 9; ++k) Rw3[k] = Rw[k];
            pw3[0] = pw[0]; pw3[1] = pw[1]; pw3[2] = pw[2];
        }
    }
}

} // namespace

extern "C" void kernel_launch(void* const* d_in, const int* in_sizes, int n_in,
                              void* d_out, int out_size, void* d_ws, size_t ws_size,
                              hipStream_t stream) {
    const float* angles = (const float*)d_in[0];   // [B, 16, 6] f32
    const float* xyz    = (const float*)d_in[1];   // [1, 16, 3] f32
    float* out          = (float*)d_out;           // [B, 16, 3] f32

    const int batch = in_sizes[0] / (NJ * 6);
    dim3 grid((batch + 255) / 256);
    skel_kernel<<<grid, 256, 0, stream>>>(angles, xyz, out, batch);
}

// Round 6
// 175.565 us; speedup vs baseline: 1.8050x; 1.8050x over previous
//
#include <hip/hip_runtime.h>

// Skeleton forward kinematics: angles [B,16,6] f32, xyz [1,16,3] f32 -> out [B,16,3] f32.
// R9: SHRINK THE INPUT REGISTER FILE VIA PRIVATE-LDS SPILL. Evidence chain:
//   R3 (64us/disp): VGPR=132 -> 3 waves/SIMD. 17% VALU, 19% HBM, occ 10%: latency/
//       concurrency-bound. 100MB real traffic; floor at high occupancy ~35-40us.
//   R4/R6: store coalescing NULL twice -> VMEM request rate is not the bottleneck.
//   R5/R8: __launch_bounds__(256,4) -> allocator collapses to VGPR=64 + cascade spill
//       (FETCH 313MB/WRITE 278MB in R8). NEVER specify min-waves on this kernel.
//       BUT both runs sustained 2.7-3.15 TB/s at 35-37% occupancy -> fill concurrency
//       scales with resident waves. VGPR<=128 must be reached NATURALLY.
//   R7: temporal prefetch split -> VGPR 144. Allocator punishes multi-phase prefetch.
// This round: spatial split. Joints 0..9 (60 floats) stay in registers (R3-identical);
// joints 10..15 (36 floats) go to a thread-PRIVATE LDS row (no syncthreads, LDS used as
// reg-file overflow). All 24 global loads still issue together up top (same MLP as R3);
// the 9 staged float4 regs die at the ds_write. Peak live ~116 regs. LDS row stride 38
// floats: 8B-aligned b64 ops, bank stride 6 (2-way base, free), 38912 B/block -> 4
// blocks/CU fits 152KB <= 160KB. Edges 10..15 re-read 6 floats from LDS (~120cy, hidden).

namespace {

constexpr int NJ = 16;
constexpr int RSTR = 38;   // LDS row stride in floats (8B-aligned rows, bank stride 6)

__device__ __forceinline__ void rot6d(const float* __restrict__ a, float R[9]) {
    float inv1 = rsqrtf(a[0]*a[0] + a[1]*a[1] + a[2]*a[2]);
    float b10 = a[0]*inv1, b11 = a[1]*inv1, b12 = a[2]*inv1;
    float d = b10*a[3] + b11*a[4] + b12*a[5];
    float c0 = a[3] - d*b10, c1 = a[4] - d*b11, c2 = a[5] - d*b12;
    float inv2 = rsqrtf(c0*c0 + c1*c1 + c2*c2);
    float b20 = c0*inv2, b21 = c1*inv2, b22 = c2*inv2;
    R[0] = b10; R[1] = b11; R[2] = b12;
    R[3] = b20; R[4] = b21; R[5] = b22;
    R[6] = b11*b22 - b12*b21;
    R[7] = b12*b20 - b10*b22;
    R[8] = b10*b21 - b11*b20;
}

__global__ __launch_bounds__(256) void skel_kernel(
    const float* __restrict__ angles,
    const float* __restrict__ xyz,
    float* __restrict__ out,
    int batch)
{
    __shared__ float stage[256 * RSTR];   // 38912 B, thread-private rows

    const int tid = threadIdx.x;
    const int b = blockIdx.x * 256 + tid;
    if (b >= batch) return;               // safe: no barriers in this kernel

    const float4* a4 = (const float4*)(angles + (size_t)b * (NJ * 6));

    // ---- issue ALL 24 loads together (max MLP, same as R3) ----
    float4 v[15];                          // joints 0..9  -> registers
#pragma unroll
    for (int k = 0; k < 15; ++k) v[k] = a4[k];
    float4 w[9];                           // joints 10..15 -> LDS spill
#pragma unroll
    for (int k = 0; k < 9; ++k) w[k] = a4[15 + k];

    // Fence: loads may not sink into the dependent chain.
    __builtin_amdgcn_sched_barrier(0);

    float af[60];
#pragma unroll
    for (int k = 0; k < 15; ++k) {
        af[4*k + 0] = v[k].x; af[4*k + 1] = v[k].y;
        af[4*k + 2] = v[k].z; af[4*k + 3] = v[k].w;
    }

    // spill joints 10..15 to this thread's private LDS row; w[] regs die here
    float* row = &stage[tid * RSTR];
#pragma unroll
    for (int k = 0; k < 9; ++k) {
        *(float2*)&row[4*k + 0] = make_float2(w[k].x, w[k].y);
        *(float2*)&row[4*k + 2] = make_float2(w[k].z, w[k].w);
    }
    // Fence: pin the ds_writes here so w's live ranges end now.
    __builtin_amdgcn_sched_barrier(0);

    float* ob = out + (size_t)b * (NJ * 3);

    float R[9], Rw[9], pw[3], Rw3[9], pw3[3];

    // ---- joint 0 ----
    rot6d(&af[0], Rw);
    {
        float x = xyz[0], y = xyz[1], z = xyz[2];
        pw[0] = Rw[0]*x + Rw[1]*y + Rw[2]*z;
        pw[1] = Rw[3]*x + Rw[4]*y + Rw[5]*z;
        pw[2] = Rw[6]*x + Rw[7]*y + Rw[8]*z;
    }
    ob[0] = pw[0]; ob[1] = pw[1]; ob[2] = pw[2];

    // tree edges (parent -> child = e+1); chains 0-1-2-3, 3-4-5, 3-6..10, 3-11..15
    constexpr int PAR[15] = {0, 1, 2, 3, 4, 3, 6, 7, 8, 9, 3, 11, 12, 13, 14};

#pragma unroll
    for (int e = 0; e < 15; ++e) {
        const int c = e + 1;
        const int p = PAR[e];

        if (p == 3) {  // branch restart: restore saved state at joint 3
#pragma unroll
            for (int k = 0; k < 9; ++k) Rw[k] = Rw3[k];
            pw[0] = pw3[0]; pw[1] = pw3[1]; pw[2] = pw3[2];
        }

        // angle source: registers for joints 1..9, private LDS row for 10..15
        float a6[6];
        const float* ap;
        if (c < 10) {
            ap = &af[c * 6];
        } else {
            float2 q0 = *(const float2*)&row[(c - 10) * 6 + 0];
            float2 q1 = *(const float2*)&row[(c - 10) * 6 + 2];
            float2 q2 = *(const float2*)&row[(c - 10) * 6 + 4];
            a6[0] = q0.x; a6[1] = q0.y; a6[2] = q1.x;
            a6[3] = q1.y; a6[4] = q2.x; a6[5] = q2.y;
            ap = a6;
        }

        rot6d(ap, R);

        // t = ref[c] - ref[p] (wave-uniform scalar loads)
        float tx = xyz[c * 3 + 0] - xyz[p * 3 + 0];
        float ty = xyz[c * 3 + 1] - xyz[p * 3 + 1];
        float tz = xyz[c * 3 + 2] - xyz[p * 3 + 2];

        // local_t = R @ t
        float lt0 = R[0]*tx + R[1]*ty + R[2]*tz;
        float lt1 = R[3]*tx + R[4]*ty + R[5]*tz;
        float lt2 = R[6]*tx + R[7]*ty + R[8]*tz;

        // pw[c] = Rw[p] @ local_t + pw[p]
        float np0 = Rw[0]*lt0 + Rw[1]*lt1 + Rw[2]*lt2 + pw[0];
        float np1 = Rw[3]*lt0 + Rw[4]*lt1 + Rw[5]*lt2 + pw[1];
        float np2 = Rw[6]*lt0 + Rw[7]*lt1 + Rw[8]*lt2 + pw[2];

        // Rw[c] = Rw[p] @ R[c]
        float T[9];
#pragma unroll
        for (int i = 0; i < 3; ++i)
#pragma unroll
            for (int j = 0; j < 3; ++j)
                T[i*3 + j] = Rw[i*3 + 0]*R[0*3 + j]
                           + Rw[i*3 + 1]*R[1*3 + j]
                           + Rw[i*3 + 2]*R[2*3 + j];
#pragma unroll
        for (int k = 0; k < 9; ++k) Rw[k] = T[k];
        pw[0] = np0; pw[1] = np1; pw[2] = np2;

        // store immediately (fire-and-forget)
        ob[c*3 + 0] = np0; ob[c*3 + 1] = np1; ob[c*3 + 2] = np2;

        if (c == 3) {  // save branch point (children 4, 6, 11)
#pragma unroll
            for (int k = 0; k < 9; ++k) Rw3[k] = Rw[k];
            pw3[0] = pw[0]; pw3[1] = pw[1]; pw3[2] = pw[2];
        }
    }
}

} // namespace

extern "C" void kernel_launch(void* const* d_in, const int* in_sizes, int n_in,
                              void* d_out, int out_size, void* d_ws, size_t ws_size,
                              hipStream_t stream) {
    const float* angles = (const float*)d_in[0];   // [B, 16, 6] f32
    const float* xyz    = (const float*)d_in[1];   // [1, 16, 3] f32
    float* out          = (float*)d_out;           // [B, 16, 3] f32

    const int batch = in_sizes[0] / (NJ * 6);
    dim3 grid((batch + 255) / 256);
    skel_kernel<<<grid, 256, 0, stream>>>(angles, xyz, out, batch);
}

// Round 7
// 170.027 us; speedup vs baseline: 1.8638x; 1.0326x over previous
//
#include <hip/hip_runtime.h>

// Skeleton forward kinematics: angles [B,16,6] f32, xyz [1,16,3] f32 -> out [B,16,3] f32.
// R10: COALESCED LOADS VIA LDS TRANSPOSE. Evidence chain:
//   R3/R6/R9 all ~64-65us/dispatch despite: store coalescing (R6 null), 2.3x occupancy
//   (R9 null). R5/R8 proved the chip sustains 2.7-3.15 TB/s on COALESCED (scratch)
//   traffic. Only common feature of the 64us runs: 24 uncoalesced gather-loads/element
//   (64 lines per instruction, each line touched 4x). Model: a gather pins ~64 fill
//   slots for ~900cy; ~128-256 slots/CU -> only 2-4 gathers in flight per CU regardless
//   of waves -> ~48us floor from loads alone. Fix the LOADS (never yet tried):
//   1 wave / 64 elements per block; 24 fully-coalesced dwordx4 (16 lines/instr, each
//   line once) -> LDS rows (stride 97 floats: +1 pad -> read bank (lane+off)%32, 2-way
//   = free; writes ~conflict-free). Chain reads angles from LDS row; af[] register file
//   gone. Stores remain scalar fire-and-forget (R6 proved coalescing them is null).
//   NO __launch_bounds__ min-waves (R5/R8: allocator collapse). LDS 24832B -> 6 wg/CU.

namespace {

constexpr int NJ = 16;
constexpr int RSTR = 97;   // padded LDS row stride in floats (97%32=1 -> 2-way banks, free)

__device__ __forceinline__ void rot6d(const float* __restrict__ a, float R[9]) {
    float inv1 = rsqrtf(a[0]*a[0] + a[1]*a[1] + a[2]*a[2]);
    float b10 = a[0]*inv1, b11 = a[1]*inv1, b12 = a[2]*inv1;
    float d = b10*a[3] + b11*a[4] + b12*a[5];
    float c0 = a[3] - d*b10, c1 = a[4] - d*b11, c2 = a[5] - d*b12;
    float inv2 = rsqrtf(c0*c0 + c1*c1 + c2*c2);
    float b20 = c0*inv2, b21 = c1*inv2, b22 = c2*inv2;
    R[0] = b10; R[1] = b11; R[2] = b12;
    R[3] = b20; R[4] = b21; R[5] = b22;
    R[6] = b11*b22 - b12*b21;
    R[7] = b12*b20 - b10*b22;
    R[8] = b10*b21 - b11*b20;
}

__global__ __launch_bounds__(64) void skel_kernel(
    const float* __restrict__ angles,
    const float* __restrict__ xyz,
    float* __restrict__ out,
    int batch)
{
    __shared__ float s[64 * RSTR];   // 24832 B

    const int l = threadIdx.x;                 // lane 0..63 (one wave per block)
    const int ebase = blockIdx.x * 64;         // first element of this block
    const int nvalid = batch - ebase;          // >0 by grid construction
    const int maxm = (nvalid >= 64) ? (64 * 24) : (nvalid * 24);

    // ---- coalesced stage: 24 x dwordx4, lane-consecutive addresses ----
    // float4 #m of the block's 24KB region; m = k*64 + l -> 16 lines/instr, each once.
    const float4* g4 = (const float4*)(angles + (size_t)ebase * (NJ * 6));
    float4 v[24];
#pragma unroll
    for (int k = 0; k < 24; ++k) {
        int m = k * 64 + l;
        if (m >= maxm) m = maxm - 1;           // clamp for partial tail (no-op for full blocks)
        v[k] = g4[m];
    }
    // Fence: all 24 loads issue before any dependent LDS write (max fill MLP).
    __builtin_amdgcn_sched_barrier(0);

    // transpose into padded rows: float F of region (F = 4m+d, elem e=F/96, off j=F%96)
    // lands at LDS addr e*97 + j == F + F/96. 4 floats of one float4 share a row.
#pragma unroll
    for (int k = 0; k < 24; ++k) {
        const int m = k * 64 + l;              // own slot (unclamped; LDS has 64 rows)
        const int A = 4 * m + m / 24;          // = e*RSTR + j
        s[A + 0] = v[k].x; s[A + 1] = v[k].y;
        s[A + 2] = v[k].z; s[A + 3] = v[k].w;
    }
    __syncthreads();

    if (l < nvalid) {
        const float* row = &s[l * RSTR];       // this thread's 96 angle floats
        float* ob = out + (size_t)(ebase + l) * (NJ * 3);

        float R[9], Rw[9], pw[3], Rw3[9], pw3[3];

        // ---- joint 0 ----
        rot6d(&row[0], Rw);
        {
            float x = xyz[0], y = xyz[1], z = xyz[2];
            pw[0] = Rw[0]*x + Rw[1]*y + Rw[2]*z;
            pw[1] = Rw[3]*x + Rw[4]*y + Rw[5]*z;
            pw[2] = Rw[6]*x + Rw[7]*y + Rw[8]*z;
        }
        ob[0] = pw[0]; ob[1] = pw[1]; ob[2] = pw[2];

        // tree edges (child = e+1); chains 0-1-2-3, 3-4-5, 3-6..10, 3-11..15
        constexpr int PAR[15] = {0, 1, 2, 3, 4, 3, 6, 7, 8, 9, 3, 11, 12, 13, 14};

#pragma unroll
        for (int e = 0; e < 15; ++e) {
            const int c = e + 1;
            const int p = PAR[e];

            if (p == 3) {  // branch restart: restore saved state at joint 3
#pragma unroll
                for (int k = 0; k < 9; ++k) Rw[k] = Rw3[k];
                pw[0] = pw3[0]; pw[1] = pw3[1]; pw[2] = pw3[2];
            }

            rot6d(&row[c * 6], R);   // 6 LDS reads, banks (lane+off)%32 -> 2-way, free

            // t = ref[c] - ref[p] (wave-uniform scalar loads)
            float tx = xyz[c * 3 + 0] - xyz[p * 3 + 0];
            float ty = xyz[c * 3 + 1] - xyz[p * 3 + 1];
            float tz = xyz[c * 3 + 2] - xyz[p * 3 + 2];

            // local_t = R @ t
            float lt0 = R[0]*tx + R[1]*ty + R[2]*tz;
            float lt1 = R[3]*tx + R[4]*ty + R[5]*tz;
            float lt2 = R[6]*tx + R[7]*ty + R[8]*tz;

            // pw[c] = Rw[p] @ local_t + pw[p]
            float np0 = Rw[0]*lt0 + Rw[1]*lt1 + Rw[2]*lt2 + pw[0];
            float np1 = Rw[3]*lt0 + Rw[4]*lt1 + Rw[5]*lt2 + pw[1];
            float np2 = Rw[6]*lt0 + Rw[7]*lt1 + Rw[8]*lt2 + pw[2];

            // Rw[c] = Rw[p] @ R[c]
            float T[9];
#pragma unroll
            for (int i = 0; i < 3; ++i)
#pragma unroll
                for (int j = 0; j < 3; ++j)
                    T[i*3 + j] = Rw[i*3 + 0]*R[0*3 + j]
                               + Rw[i*3 + 1]*R[1*3 + j]
                               + Rw[i*3 + 2]*R[2*3 + j];
#pragma unroll
            for (int k = 0; k < 9; ++k) Rw[k] = T[k];
            pw[0] = np0; pw[1] = np1; pw[2] = np2;

            // store immediately (fire-and-forget; R6 proved coalescing these is null)
            ob[c*3 + 0] = np0; ob[c*3 + 1] = np1; ob[c*3 + 2] = np2;

            if (c == 3) {  // save branch point (children 4, 6, 11)
#pragma unroll
                for (int k = 0; k < 9; ++k) Rw3[k] = Rw[k];
                pw3[0] = pw[0]; pw3[1] = pw[1]; pw3[2] = pw[2];
            }
        }
    }
}

} // namespace

extern "C" void kernel_launch(void* const* d_in, const int* in_sizes, int n_in,
                              void* d_out, int out_size, void* d_ws, size_t ws_size,
                              hipStream_t stream) {
    const float* angles = (const float*)d_in[0];   // [B, 16, 6] f32
    const float* xyz    = (const float*)d_in[1];   // [1, 16, 3] f32
    float* out          = (float*)d_out;           // [B, 16, 3] f32

    const int batch = in_sizes[0] / (NJ * 6);
    dim3 grid((batch + 63) / 64);
    skel_kernel<<<grid, 64, 0, stream>>>(angles, xyz, out, batch);
}